// Round 11
// baseline (221.976 us; speedup 1.0000x reference)
//
#include <hip/hip_runtime.h>
#include <math.h>

typedef unsigned short u16;
typedef unsigned int u32;

#define NCAM 6
#define NHEADS 8
#define NPOINTS 4
#define DD 256
#define HH 20
#define WW 40
#define HWSZ 800
#define LQ 4800
#define HDIM 32

typedef __attribute__((ext_vector_type(8))) short bf16x8;
typedef __attribute__((ext_vector_type(4))) float f32x4;

__device__ __forceinline__ u16 f2b(float x) {
    union { float f; u32 u; } v;
    v.f = x;
    u32 r = (v.u + 0x7FFFu + ((v.u >> 16) & 1u)) >> 16;  // RNE
    return (u16)r;
}
__device__ __forceinline__ float lo2f(u32 u) {
    union { u32 u; float f; } v; v.u = u << 16; return v.f;
}
__device__ __forceinline__ float hi2f(u32 u) {
    union { u32 u; float f; } v; v.u = u & 0xFFFF0000u; return v.f;
}
__device__ __forceinline__ float red16(float s) {
    s += __shfl_xor(s, 1);
    s += __shfl_xor(s, 2);
    s += __shfl_xor(s, 4);
    s += __shfl_xor(s, 8);
    return s;
}
// async global->LDS, 16B per lane, dest = base + lane*16 (wave-uniform base)
__device__ __forceinline__ void gl_lds16(const void* g, void* l) {
    __builtin_amdgcn_global_load_lds(
        (const __attribute__((address_space(1))) void*)g,
        (__attribute__((address_space(3))) void*)l, 16, 0, 0);
}

// k-major layouts: elem(row,k) at ((k>>3)*NR + row)*8 + (k&7)

// ---------------------------------------------------------------------------
// prep: one-shot heterogeneous prep (identical to R9-passing version).
#define P1_BLOCKS 3362
__global__ __launch_bounds__(256) void prep(
    const float* __restrict__ x, const float* __restrict__ conv0_w,
    const float* __restrict__ conv0_b, const float* __restrict__ key_w,
    const float* __restrict__ key_b, const float* __restrict__ val_w,
    const float* __restrict__ val_b, const float* __restrict__ off_w,
    const float* __restrict__ off_b, const float* __restrict__ lin1_w,
    const float* __restrict__ lin2_w, const float* __restrict__ conv1_w,
    const float* __restrict__ conv1_b, const float* __restrict__ out_w,
    const float* __restrict__ out_b, const float* __restrict__ cam_emb,
    float* __restrict__ pos, u16* __restrict__ xtb_t, float* __restrict__ mu_x,
    u16* __restrict__ Wcat_t, float* __restrict__ bias_cat,
    u16* __restrict__ lin1b_t, u16* __restrict__ lin2b_t,
    u16* __restrict__ wcombb_t, float* __restrict__ bcomb,
    float* __restrict__ camoff, float* __restrict__ posy,
    float* __restrict__ posx) {
    __shared__ float sbuf[1088];
    __shared__ __align__(16) u16 As2[1024];
    __shared__ __align__(16) u16 Bs2[4096];
    int b = blockIdx.x, t = threadIdx.x;
    if (b < 800) {
        int hw = b, d = t;
        int h = hw / WW, w = hw % WW;
        int j = (d & 127) >> 1;
        float dim = powf(10000.0f, (float)j * (1.0f / 64.0f));
        float v;
        if (d < 128) v = (float)(h + 1) / (20.0f + 1e-6f) * (2.0f * (float)M_PI);
        else         v = (float)(w + 1) / (40.0f + 1e-6f) * (2.0f * (float)M_PI);
        float p = v / dim;
        pos[hw * DD + d] = (d & 1) ? cosf(p) : sinf(p);
    } else if (b < 1184) {
        int row = (b - 800) * 4 + (t >> 6);
        int lane = t & 63;
        const float* base = x + (size_t)row * HWSZ;
        float s = 0.f;
        for (int i = lane; i < HWSZ; i += 64) s += base[i];
#pragma unroll
        for (int m = 1; m <= 32; m <<= 1) s += __shfl_xor(s, m);
        if (lane == 0) mu_x[row] = s * (1.0f / (float)HWSZ);
    } else if (b < 1952) {
        int i = (b - 1184) * 256 + t;
        if (i < 65536) {
            int n = i >> 8, k = i & 255;
            Wcat_t[(((size_t)(k >> 3)) * 1152 + n) * 8 + (k & 7)] = f2b(conv0_w[i]);
            if (i < 256) bias_cat[i] = conv0_b[i];
        } else if (i < 131072) {
            int j = i - 65536;
            int n = j >> 8, k = j & 255;
            lin1b_t[(((size_t)(k >> 3)) * 256 + n) * 8 + (k & 7)] = f2b(lin1_w[j]);
        } else {
            int j = i - 131072;
            int n = j >> 8, k = j & 255;
            lin2b_t[(((size_t)(k >> 3)) * 256 + n) * 8 + (k & 7)] = f2b(lin2_w[j]);
        }
    } else if (b < 3152) {
        int idx = b - 1952;
        int cam = idx / 200, rem = idx % 200;
        int hw0 = (rem % 25) * 32, c0 = (rem / 25) * 32;
        float (*tile)[33] = (float(*)[33])sbuf;
        int lhw = t & 31, lc4 = t >> 5;
#pragma unroll
        for (int i = 0; i < 4; ++i) {
            int lc = lc4 * 4 + i;
            tile[lc][lhw] = x[((size_t)(cam * DD + c0 + lc)) * HWSZ + hw0 + lhw];
        }
        __syncthreads();
        int lc2 = t & 31, lhw4 = t >> 5;
        int c = c0 + lc2;
#pragma unroll
        for (int i = 0; i < 4; ++i) {
            int lhw2 = lhw4 * 4 + i;
            int row = cam * HWSZ + hw0 + lhw2;
            xtb_t[(((size_t)(c >> 3)) * 4800 + row) * 8 + (c & 7)] =
                f2b(tile[lc2][lhw2]);
        }
    } else if (b < 3212) {
        int idx = b - 3152;
        int yside = (idx < 20);
        int coord = yside ? idx : idx - 20;
        if (t < 128) {
            int d = t, j = d >> 1;
            float dim = powf(10000.0f, (float)j * (1.0f / 64.0f));
            float v = yside
                ? (float)(coord + 1) / (20.0f + 1e-6f) * (2.0f * (float)M_PI)
                : (float)(coord + 1) / (40.0f + 1e-6f) * (2.0f * (float)M_PI);
            float p = v / dim;
            sbuf[d] = (d & 1) ? cosf(p) : sinf(p);
        }
        __syncthreads();
        int koff = yside ? 0 : 128;
        float* outp = yside ? (posy + coord * 384) : (posx + coord * 384);
        int l = t & 15, og = t >> 4;
#pragma unroll
        for (int chunk = 0; chunk < 24; ++chunk) {
            int n = chunk * 16 + og;
            const float* wr = off_w + (size_t)n * 256 + koff + l * 8;
            float4 w0 = *(const float4*)wr;
            float4 w1 = *(const float4*)(wr + 4);
            const float* pv = sbuf + l * 8;
            float s = pv[0] * w0.x + pv[1] * w0.y + pv[2] * w0.z + pv[3] * w0.w +
                      pv[4] * w1.x + pv[5] * w1.y + pv[6] * w1.z + pv[7] * w1.w;
            s = red16(s);
            if (l == 0) outp[n] = s;
        }
    } else if (b < 3218) {
        int cam = b - 3212;
        sbuf[t] = cam_emb[cam * DD + t];
        __syncthreads();
        int l = t & 15, og = t >> 4;
#pragma unroll
        for (int chunk = 0; chunk < 24; ++chunk) {
            int n = chunk * 16 + og;
            const float* wr = off_w + (size_t)n * 256 + l * 16;
            float s = 0.f;
#pragma unroll
            for (int i = 0; i < 4; ++i) {
                float4 w4 = *(const float4*)(wr + i * 4);
                const float* ce = sbuf + l * 16 + i * 4;
                s += ce[0] * w4.x + ce[1] * w4.y + ce[2] * w4.z + ce[3] * w4.w;
            }
            s = red16(s);
            if (l == 0) camoff[cam * 384 + n] = s;
        }
    } else if (b < 3274) {
        sbuf[t] = conv0_b[t];
        __syncthreads();
        int l = t & 15, og = t >> 4;
        int rr = (b - 3218) * 16 + og;
        const float* srcp;
        float bsrc;
        if (rr < 512) {
            int head = rr >> 6, cpair = (rr >> 1) & 31, kv = rr & 1;
            srcp = (kv ? val_w : key_w) + (size_t)(head * 32 + cpair) * 256;
            bsrc = (kv ? val_b : key_b)[head * 32 + cpair];
        } else {
            srcp = off_w + (size_t)(rr - 512) * 256;
            bsrc = off_b[rr - 512];
        }
        float s = 0.f;
#pragma unroll
        for (int i = 0; i < 4; ++i) {
            float4 w4 = *(const float4*)(srcp + l * 16 + i * 4);
            const float* cb = sbuf + l * 16 + i * 4;
            s += cb[0] * w4.x + cb[1] * w4.y + cb[2] * w4.z + cb[3] * w4.w;
        }
        s = red16(s);
        if (l == 0) bias_cat[256 + rr] = bsrc + s;
    } else if (b < 3290) {
        sbuf[t] = out_b[t];
        __syncthreads();
        int l = t & 15, og = t >> 4;
        int n = (b - 3274) * 16 + og;
        float s = 0.f;
#pragma unroll
        for (int i = 0; i < 4; ++i) {
            float4 w4 = *(const float4*)(conv1_w + (size_t)n * 256 + l * 16 + i * 4);
            const float* ob = sbuf + l * 16 + i * 4;
            s += ob[0] * w4.x + ob[1] * w4.y + ob[2] * w4.z + ob[3] * w4.w;
        }
        s = red16(s);
        if (l == 0) bcomb[n] = conv1_b[n] + s;
    } else {
        int fb = b - 3290;
        int isw = (fb >= 56);
        int bb = isw ? fb - 56 : fb;
        int row0 = (bb >> 1) * 32, col0 = (bb & 1) * 128;
        int wv = t >> 6, lane = t & 63, quad = lane >> 4, l = lane & 15;
        f32x4 acc[2][2] = {};
        for (int k0 = 0; k0 < 256; k0 += 32) {
            __syncthreads();
            if (t < 128) {
                int m = t >> 2, j = t & 3;
                int rr = row0 + m;
                const float* ap;
                if (!isw) {
                    if (rr < 512) {
                        int head = rr >> 6, cpair = (rr >> 1) & 31, kv = rr & 1;
                        ap = (kv ? val_w : key_w) + (size_t)(head * 32 + cpair) * 256;
                    } else {
                        ap = off_w + (size_t)(rr - 512) * 256;
                    }
                } else {
                    ap = conv1_w + (size_t)rr * 256;
                }
                float4 f0 = *(const float4*)&ap[k0 + j * 8];
                float4 f1 = *(const float4*)&ap[k0 + j * 8 + 4];
                uint4 up;
                up.x = (u32)f2b(f0.x) | ((u32)f2b(f0.y) << 16);
                up.y = (u32)f2b(f0.z) | ((u32)f2b(f0.w) << 16);
                up.z = (u32)f2b(f1.x) | ((u32)f2b(f1.y) << 16);
                up.w = (u32)f2b(f1.z) | ((u32)f2b(f1.w) << 16);
                *(uint4*)&As2[(j * 32 + m) * 8] = up;
            }
            {
                int krel = t >> 3;
                int k = k0 + krel;
                int j = t >> 6, kin = k & 7;
                int c0l = (t & 7) * 16;
                const float* wsrc = (isw ? out_w : conv0_w) + (size_t)k * 256 + col0 + c0l;
#pragma unroll
                for (int i = 0; i < 16; i += 4) {
                    float4 f = *(const float4*)&wsrc[i];
                    Bs2[(j * 128 + c0l + i) * 8 + kin]     = f2b(f.x);
                    Bs2[(j * 128 + c0l + i + 1) * 8 + kin] = f2b(f.y);
                    Bs2[(j * 128 + c0l + i + 2) * 8 + kin] = f2b(f.z);
                    Bs2[(j * 128 + c0l + i + 3) * 8 + kin] = f2b(f.w);
                }
            }
            __syncthreads();
            bf16x8 a0 = *(const bf16x8*)&As2[(quad * 32 + l) * 8];
            bf16x8 a1 = *(const bf16x8*)&As2[(quad * 32 + 16 + l) * 8];
            bf16x8 b0v = *(const bf16x8*)&Bs2[(quad * 128 + wv * 32 + l) * 8];
            bf16x8 b1v = *(const bf16x8*)&Bs2[(quad * 128 + wv * 32 + 16 + l) * 8];
            acc[0][0] = __builtin_amdgcn_mfma_f32_16x16x32_bf16(a0, b0v, acc[0][0], 0, 0, 0);
            acc[0][1] = __builtin_amdgcn_mfma_f32_16x16x32_bf16(a0, b1v, acc[0][1], 0, 0, 0);
            acc[1][0] = __builtin_amdgcn_mfma_f32_16x16x32_bf16(a1, b0v, acc[1][0], 0, 0, 0);
            acc[1][1] = __builtin_amdgcn_mfma_f32_16x16x32_bf16(a1, b1v, acc[1][1], 0, 0, 0);
        }
#pragma unroll
        for (int mt = 0; mt < 2; ++mt) {
#pragma unroll
            for (int nt = 0; nt < 2; ++nt) {
                int c = col0 + wv * 32 + nt * 16 + l;
#pragma unroll
                for (int r = 0; r < 4; ++r) {
                    int rr = row0 + mt * 16 + quad * 4 + r;
                    u16 ov = f2b(acc[mt][nt][r]);
                    if (!isw)
                        Wcat_t[(((size_t)(c >> 3)) * 1152 + 256 + rr) * 8 + (c & 7)] = ov;
                    else
                        wcombb_t[(((size_t)(c >> 3)) * 256 + rr) * 8 + (c & 7)] = ov;
                }
            }
        }
    }
}

// ---------------------------------------------------------------------------
// gemm_fused: as R9 but kv output is fp32 (no f2b on kv path).
__global__ __launch_bounds__(256) void gemm_fused(
    const u16* __restrict__ Abt, const u16* __restrict__ Wcat_t,
    const float* __restrict__ bias_cat, const float* __restrict__ pos,
    const float* __restrict__ cam_emb, u16* __restrict__ spcb,
    float* __restrict__ kvf, float* __restrict__ offs,
    const float* __restrict__ mu_x, const float* __restrict__ conv0_w,
    const float* __restrict__ conv0_b, const float* __restrict__ conv2_w,
    const float* __restrict__ conv2_b, float* __restrict__ g) {
    int b = blockIdx.x, t = threadIdx.x;
    if (b < 675) {
        __shared__ __align__(16) u16 As[2048];
        __shared__ __align__(16) u16 Bs[4096];
        int col0 = (b % 9) * 128, row0 = (b / 9) * 64;
        int wv = t >> 6, lane = t & 63;
        int quad = lane >> 4, l = lane & 15;
        f32x4 acc[4][2] = {};
        for (int kg = 0; kg < 32; kg += 4) {
            __syncthreads();
            gl_lds16(Abt + (((size_t)(kg + wv)) * 4800 + row0 + lane) * 8,
                     &As[wv * 64 * 8]);
            int jb = wv >> 1, hb = wv & 1;
            gl_lds16(Wcat_t + (((size_t)(kg + jb)) * 1152 + col0 + hb * 64 + lane) * 8,
                     &Bs[(jb * 128 + hb * 64) * 8]);
            gl_lds16(Wcat_t + (((size_t)(kg + 2 + jb)) * 1152 + col0 + hb * 64 + lane) * 8,
                     &Bs[((2 + jb) * 128 + hb * 64) * 8]);
            __syncthreads();
            bf16x8 b0 = *(const bf16x8*)&Bs[(quad * 128 + wv * 32 + l) * 8];
            bf16x8 b1 = *(const bf16x8*)&Bs[(quad * 128 + wv * 32 + 16 + l) * 8];
#pragma unroll
            for (int mt = 0; mt < 4; ++mt) {
                bf16x8 a = *(const bf16x8*)&As[(quad * 64 + mt * 16 + l) * 8];
                acc[mt][0] = __builtin_amdgcn_mfma_f32_16x16x32_bf16(a, b0, acc[mt][0], 0, 0, 0);
                acc[mt][1] = __builtin_amdgcn_mfma_f32_16x16x32_bf16(a, b1, acc[mt][1], 0, 0, 0);
            }
        }
#pragma unroll
        for (int mt = 0; mt < 4; ++mt) {
#pragma unroll
            for (int nt = 0; nt < 2; ++nt) {
                int col = col0 + wv * 32 + nt * 16 + l;
                float bb = bias_cat[col];
#pragma unroll
                for (int r = 0; r < 4; ++r) {
                    int row = row0 + mt * 16 + quad * 4 + r;
                    float v = acc[mt][nt][r] + bb;
                    if (col0 < 256) {
                        int cam = row / HWSZ, hw = row % HWSZ;
                        spcb[(size_t)row * 256 + col] =
                            f2b(v + pos[(size_t)hw * 256 + col] + cam_emb[cam * 256 + col]);
                    } else if (col0 < 768) {
                        kvf[(size_t)row * 512 + (col - 256)] = v;
                    } else {
                        offs[(size_t)row * 384 + (col - 768)] = v;
                    }
                }
            }
        }
    } else {
        int cam = b - 675;
        __shared__ float mu[DD];
        __shared__ float smu[DD];
        float pm;
        {
            int d = t;
            int j = (d & 127) >> 1;
            float inv = 1.0f / powf(10000.0f, (float)j * (1.0f / 64.0f));
            float s = 0.f;
            if (d < 128) {
                for (int h = 0; h < HH; ++h) {
                    float p = (float)(h + 1) / (20.0f + 1e-6f) * (2.0f * (float)M_PI) * inv;
                    s += (d & 1) ? cosf(p) : sinf(p);
                }
                pm = s * (1.0f / (float)HH);
            } else {
                for (int w = 0; w < WW; ++w) {
                    float p = (float)(w + 1) / (40.0f + 1e-6f) * (2.0f * (float)M_PI) * inv;
                    s += (d & 1) ? cosf(p) : sinf(p);
                }
                pm = s * (1.0f / (float)WW);
            }
        }
        mu[t] = mu_x[cam * DD + t];
        __syncthreads();
        float a = conv0_b[t] + pm + cam_emb[cam * DD + t];
        const float* wr = conv0_w + (size_t)t * DD;
        for (int k = 0; k < DD; ++k) a += mu[k] * wr[k];
        smu[t] = a;
        __syncthreads();
        float ga = conv2_b[t];
        const float* w2r = conv2_w + (size_t)t * DD;
        for (int d = 0; d < DD; ++d) ga += smu[d] * w2r[d];
        g[cam * DD + t] = ga;
    }
}

// ---------------------------------------------------------------------------
// Deformable attention (R7-proven structure, fp32 kv): 2 q/block, 16 lanes/head
// (2 ch/lane), staged bilinear in separate 4B arrays (zero conflicts), float4
// unpack-free kv gathers, 2-cam batched online softmax.
__global__ __launch_bounds__(256, 4) void attn_kernel(
    const u16* __restrict__ spcb, const float* __restrict__ kvf,
    const float* __restrict__ offs, const float* __restrict__ posy,
    const float* __restrict__ posx, const float* __restrict__ camoff,
    const float* __restrict__ g, u16* __restrict__ attn_out) {
    int qq = blockIdx.x;
    int q0 = qq * 2;
    int tid = threadIdx.x;
    int cam = q0 / HWSZ;
    int hw0 = q0 % HWSZ;
    __shared__ float soff[2][384];
    __shared__ float wgt[2][192][4];
    __shared__ int   idxp[2][192][4];
    for (int i = tid; i < 768; i += 256) {
        int qi = i / 384, n = i - qi * 384;
        int hw = hw0 + qi;
        int h = hw / WW, w = hw - h * WW;
        soff[qi][n] = offs[(size_t)(q0 + qi) * 384 + n] + posy[h * 384 + n] +
                      posx[w * 384 + n] + camoff[cam * 384 + n];
    }
    __syncthreads();
    for (int e2 = tid; e2 < 384; e2 += 256) {
        int qi = e2 / 192, e = e2 - qi * 192;
        int head = e / 24, r = e - head * 24;
        int scam = r >> 2;
        int hw = hw0 + qi;
        int h = hw / WW, w = hw - h * WW;
        float X = (float)w + soff[qi][e * 2];
        float Y = (float)h + soff[qi][e * 2 + 1];
        float x0f = floorf(X), y0f = floorf(Y);
        float fx = X - x0f, fy = Y - y0f;
        int x0 = (int)x0f, y0 = (int)y0f, x1 = x0 + 1, y1 = y0 + 1;
        float vx0 = (x0 >= 0 && x0 < WW) ? 1.f : 0.f;
        float vx1 = (x1 >= 0 && x1 < WW) ? 1.f : 0.f;
        float vy0 = (y0 >= 0 && y0 < HH) ? 1.f : 0.f;
        float vy1 = (y1 >= 0 && y1 < HH) ? 1.f : 0.f;
        int cx0 = min(max(x0, 0), WW - 1), cx1 = min(max(x1, 0), WW - 1);
        int cy0 = min(max(y0, 0), HH - 1), cy1 = min(max(y1, 0), HH - 1);
        wgt[qi][e][0] = (1.f - fx) * (1.f - fy) * vx0 * vy0;
        wgt[qi][e][1] = fx * (1.f - fy) * vx1 * vy0;
        wgt[qi][e][2] = (1.f - fx) * fy * vx0 * vy1;
        wgt[qi][e][3] = fx * fy * vx1 * vy1;
        int pb = scam * HWSZ, hb = head * 64;
        idxp[qi][e][0] = ((pb + cy0 * WW + cx0) << 9) + hb;
        idxp[qi][e][1] = ((pb + cy0 * WW + cx1) << 9) + hb;
        idxp[qi][e][2] = ((pb + cy1 * WW + cx0) << 9) + hb;
        idxp[qi][e][3] = ((pb + cy1 * WW + cx1) << 9) + hb;
    }
    __syncthreads();
    int qi = tid >> 7, head = (tid >> 4) & 7, l = tid & 15;
    int q = q0 + qi;
    int c0 = l * 2;
    u32 qu = *(const u32*)&spcb[(size_t)q * 256 + head * 32 + c0];
    const float scale = 0.17677669529663687f;  // 1/sqrt(32)
    float q0s = lo2f(qu) * scale, q1s = hi2f(qu) * scale;
    float m = -1e30f, den = 0.f, o0 = 0.f, o1 = 0.f;
    int l4 = 4 * l;
    for (int scp = 0; scp < 3; ++scp) {
        int e0i = head * 24 + scp * 8;
        float av0[8], av1[8], lg[8];
#pragma unroll
        for (int p = 0; p < 8; ++p) {
            int e = e0i + p;
            float ak0 = 0.f, ak1 = 0.f, a0 = 0.f, a1 = 0.f;
#pragma unroll
            for (int j = 0; j < 4; ++j) {
                float wj = wgt[qi][e][j];
                int idx = idxp[qi][e][j] + l4;
                float4 d = *(const float4*)&kvf[idx];  // k0,v0,k1,v1 (fp32)
                ak0 += wj * d.x;
                a0  += wj * d.y;
                ak1 += wj * d.z;
                a1  += wj * d.w;
            }
            av0[p] = a0; av1[p] = a1;
            float pl = q0s * ak0 + q1s * ak1;
            lg[p] = red16(pl);
        }
        float2 gva = *(const float2*)&g[(scp * 2) * 256 + head * 32 + c0];
        float2 gvb = *(const float2*)&g[(scp * 2 + 1) * 256 + head * 32 + c0];
        float pga = red16(q0s * gva.x + q1s * gva.y);
        float pgb = red16(q0s * gvb.x + q1s * gvb.y);
        float mc = fmaxf(pga, pgb);
#pragma unroll
        for (int p = 0; p < 8; ++p) mc = fmaxf(mc, lg[p]);
        float mn = fmaxf(m, mc);
        float aa = __expf(m - mn);
        float ee[8];
        float dsum = 0.f, s0 = 0.f, s1 = 0.f;
#pragma unroll
        for (int p = 0; p < 8; ++p) {
            ee[p] = __expf(lg[p] - mn);
            dsum += ee[p];
            s0 += ee[p] * av0[p];
            s1 += ee[p] * av1[p];
        }
        float ea = __expf(pga - mn), eb = __expf(pgb - mn);
        dsum += ea + eb;
        s0 += ea * gva.x + eb * gvb.x;
        s1 += ea * gva.y + eb * gvb.y;
        den = den * aa + dsum;
        o0 = o0 * aa + s0;
        o1 = o1 * aa + s1;
        m = mn;
    }
    float inv = 1.f / den;
    u32 pack = (u32)f2b(o0 * inv) | ((u32)f2b(o1 * inv) << 16);
    *(u32*)&attn_out[(size_t)q * 256 + head * 32 + c0] = pack;
}

// ---------------------------------------------------------------------------
// Mega-epilogue (identical to R9-passing version)
__global__ __launch_bounds__(256) void epilogue(
    const u16* __restrict__ Ab, const u16* __restrict__ Wc_t,
    const float* __restrict__ bcomb, const float* __restrict__ x_nchw,
    const float* __restrict__ n0g, const float* __restrict__ n0b,
    const u16* __restrict__ W1_t, const float* __restrict__ b1v,
    const u16* __restrict__ W2_t, const float* __restrict__ b2v,
    const float* __restrict__ n2g, const float* __restrict__ n2b,
    float* __restrict__ out_nchw) {
    __shared__ __align__(16) u16 As[552];
    __shared__ __align__(16) u16 Bs[8192];
    __shared__ __align__(16) u16 A2[4360];
    __shared__ float red[4][4][4][2];
    int t = threadIdx.x;
    int row0 = blockIdx.x * 16;
    int wv = t >> 6, lane = t & 63, quad = lane >> 4, l = lane & 15;
    int cam = row0 / HWSZ;
    int hw0q = row0 % HWSZ + quad * 4;

    f32x4 acc[4] = {};
    for (int kg = 0; kg < 32; kg += 4) {
        __syncthreads();
        if (t < 64) {
            int mm = t >> 2, j = t & 3;
            *(uint4*)&As[(j * 17 + mm) * 8] =
                *(const uint4*)&Ab[(size_t)(row0 + mm) * 256 + kg * 8 + j * 8];
        }
#pragma unroll
        for (int s = 0; s < 4; ++s)
            gl_lds16(Wc_t + (((size_t)(kg + wv)) * 256 + s * 64 + lane) * 8,
                     &Bs[(wv * 256 + s * 64) * 8]);
        __syncthreads();
        bf16x8 a = *(const bf16x8*)&As[(quad * 17 + l) * 8];
#pragma unroll
        for (int nt = 0; nt < 4; ++nt) {
            bf16x8 b = *(const bf16x8*)&Bs[(quad * 256 + wv * 64 + nt * 16 + l) * 8];
            acc[nt] = __builtin_amdgcn_mfma_f32_16x16x32_bf16(a, b, acc[nt], 0, 0, 0);
        }
    }
    float v[4][4];
    int cols[4];
#pragma unroll
    for (int nt = 0; nt < 4; ++nt) {
        int col = wv * 64 + nt * 16 + l;
        cols[nt] = col;
        float bb = bcomb[col];
        float4 rx = *(const float4*)&x_nchw[((size_t)(cam * 256 + col)) * HWSZ + hw0q];
        v[nt][0] = acc[nt][0] + bb + rx.x;
        v[nt][1] = acc[nt][1] + bb + rx.y;
        v[nt][2] = acc[nt][2] + bb + rx.z;
        v[nt][3] = acc[nt][3] + bb + rx.w;
    }
#pragma unroll
    for (int r = 0; r < 4; ++r) {
        float s = v[0][r] + v[1][r] + v[2][r] + v[3][r];
        float sq = v[0][r] * v[0][r] + v[1][r] * v[1][r] +
                   v[2][r] * v[2][r] + v[3][r] * v[3][r];
#pragma unroll
        for (int msk = 1; msk <= 8; msk <<= 1) {
            s += __shfl_xor(s, msk);
            sq += __shfl_xor(sq, msk);
        }
        if (l == 0) { red[wv][quad][r][0] = s; red[wv][quad][r][1] = sq; }
    }
    __syncthreads();
    float o0[4][4];
#pragma unroll
    for (int r = 0; r < 4; ++r) {
        float S = red[0][quad][r][0] + red[1][quad][r][0] +
                  red[2][quad][r][0] + red[3][quad][r][0];
        float Q = red[0][quad][r][1] + red[1][quad][r][1] +
                  red[2][quad][r][1] + red[3][quad][r][1];
        float mean = S * (1.0f / 256.0f);
        float var = Q * (1.0f / 256.0f) - mean * mean;
        float rstd = rsqrtf(var + 1e-5f);
        int row = quad * 4 + r;
#pragma unroll
        for (int nt = 0; nt < 4; ++nt) {
            int col = cols[nt];
            float ov = (v[nt][r] - mean) * rstd * n0g[col] + n0b[col];
            o0[nt][r] = ov;
            A2[((col >> 3) * 17 + row) * 8 + (col & 7)] = f2b(ov);
        }
    }
    f32x4 acc2[4] = {};
    for (int kg = 0; kg < 32; kg += 4) {
        __syncthreads();
#pragma unroll
        for (int s = 0; s < 4; ++s)
            gl_lds16(W1_t + (((size_t)(kg + wv)) * 256 + s * 64 + lane) * 8,
                     &Bs[(wv * 256 + s * 64) * 8]);
        __syncthreads();
        bf16x8 a = *(const bf16x8*)&A2[((kg + quad) * 17 + l) * 8];
#pragma unroll
        for (int nt = 0; nt < 4; ++nt) {
            bf16x8 b = *(const bf16x8*)&Bs[(quad * 256 + wv * 64 + nt * 16 + l) * 8];
            acc2[nt] = __builtin_amdgcn_mfma_f32_16x16x32_bf16(a, b, acc2[nt], 0, 0, 0);
        }
    }
    __syncthreads();
#pragma unroll
    for (int nt = 0; nt < 4; ++nt) {
        int col = cols[nt];
        float bb = b1v[col];
#pragma unroll
        for (int r = 0; r < 4; ++r) {
            int row = quad * 4 + r;
            A2[((col >> 3) * 17 + row) * 8 + (col & 7)] = f2b(fmaxf(acc2[nt][r] + bb, 0.f));
        }
    }
    f32x4 acc3[4] = {};
    for (int kg = 0; kg < 32; kg += 4) {
        __syncthreads();
#pragma unroll
        for (int s = 0; s < 4; ++s)
            gl_lds16(W2_t + (((size_t)(kg + wv)) * 256 + s * 64 + lane) * 8,
                     &Bs[(wv * 256 + s * 64) * 8]);
        __syncthreads();
        bf16x8 a = *(const bf16x8*)&A2[((kg + quad) * 17 + l) * 8];
#pragma unroll
        for (int nt = 0; nt < 4; ++nt) {
            bf16x8 b = *(const bf16x8*)&Bs[(quad * 256 + wv * 64 + nt * 16 + l) * 8];
            acc3[nt] = __builtin_amdgcn_mfma_f32_16x16x32_bf16(a, b, acc3[nt], 0, 0, 0);
        }
    }
    float v2[4][4];
#pragma unroll
    for (int nt = 0; nt < 4; ++nt) {
        float bb = b2v[cols[nt]];
#pragma unroll
        for (int r = 0; r < 4; ++r) v2[nt][r] = acc3[nt][r] + bb + o0[nt][r];
    }
    __syncthreads();
#pragma unroll
    for (int r = 0; r < 4; ++r) {
        float s = v2[0][r] + v2[1][r] + v2[2][r] + v2[3][r];
        float sq = v2[0][r] * v2[0][r] + v2[1][r] * v2[1][r] +
                   v2[2][r] * v2[2][r] + v2[3][r] * v2[3][r];
#pragma unroll
        for (int msk = 1; msk <= 8; msk <<= 1) {
            s += __shfl_xor(s, msk);
            sq += __shfl_xor(sq, msk);
        }
        if (l == 0) { red[wv][quad][r][0] = s; red[wv][quad][r][1] = sq; }
    }
    __syncthreads();
    float mean2[4], rstd2[4];
#pragma unroll
    for (int r = 0; r < 4; ++r) {
        float S = red[0][quad][r][0] + red[1][quad][r][0] +
                  red[2][quad][r][0] + red[3][quad][r][0];
        float Q = red[0][quad][r][1] + red[1][quad][r][1] +
                  red[2][quad][r][1] + red[3][quad][r][1];
        mean2[r] = S * (1.0f / 256.0f);
        float var = Q * (1.0f / 256.0f) - mean2[r] * mean2[r];
        rstd2[r] = rsqrtf(var + 1e-5f);
    }
#pragma unroll
    for (int nt = 0; nt < 4; ++nt) {
        int col = cols[nt];
        float gg = n2g[col], bb = n2b[col];
        float4 ov4;
        ov4.x = (v2[nt][0] - mean2[0]) * rstd2[0] * gg + bb;
        ov4.y = (v2[nt][1] - mean2[1]) * rstd2[1] * gg + bb;
        ov4.z = (v2[nt][2] - mean2[2]) * rstd2[2] * gg + bb;
        ov4.w = (v2[nt][3] - mean2[3]) * rstd2[3] * gg + bb;
        *(float4*)&out_nchw[((size_t)(cam * 256 + col)) * HWSZ + hw0q] = ov4;
    }
}

// ---------------------------------------------------------------------------
extern "C" void kernel_launch(void* const* d_in, const int* in_sizes, int n_in,
                              void* d_out, int out_size, void* d_ws, size_t ws_size,
                              hipStream_t stream) {
    const float* x       = (const float*)d_in[0];
    const float* conv0_w = (const float*)d_in[1];
    const float* conv0_b = (const float*)d_in[2];
    const float* conv2_w = (const float*)d_in[3];
    const float* conv2_b = (const float*)d_in[4];
    const float* cam_emb = (const float*)d_in[5];
    const float* off_w   = (const float*)d_in[6];
    const float* off_b   = (const float*)d_in[7];
    const float* val_w   = (const float*)d_in[8];
    const float* val_b   = (const float*)d_in[9];
    const float* key_w   = (const float*)d_in[10];
    const float* key_b   = (const float*)d_in[11];
    const float* out_w   = (const float*)d_in[12];
    const float* out_b   = (const float*)d_in[13];
    const float* conv1_w = (const float*)d_in[14];
    const float* conv1_b = (const float*)d_in[15];
    const float* norm0_g = (const float*)d_in[16];
    const float* norm0_b = (const float*)d_in[17];
    const float* lin1_w  = (const float*)d_in[18];
    const float* lin1_b  = (const float*)d_in[19];
    const float* lin2_w  = (const float*)d_in[20];
    const float* lin2_b  = (const float*)d_in[21];
    const float* norm2_g = (const float*)d_in[22];
    const float* norm2_b = (const float*)d_in[23];

    float* ws = (float*)d_ws;
    float* pos      = ws;                       // 204800
    float* mu_x     = pos + 204800;             // 1536
    float* g        = mu_x + 1536;              // 1536
    float* camoff   = g + 1536;                 // 2304
    float* posy     = camoff + 2304;            // 7680
    float* posx     = posy + 7680;              // 15360
    float* bias_cat = posx + 15360;             // 1152
    float* bcomb    = bias_cat + 1152;          // 256
    float* offs     = bcomb + 256;              // 1843200
    float* f_xtb    = offs + 1843200;           // 614400 (alias: attn_ob)
    float* f_spcb   = f_xtb + 614400;           // 614400
    float* kvf      = f_spcb + 614400;          // 2457600 (fp32 kv)
    float* f_Wcat   = kvf + 2457600;            // 147456
    float* f_lin1b  = f_Wcat + 147456;          // 32768
    float* f_lin2b  = f_lin1b + 32768;          // 32768
    float* f_wcombb = f_lin2b + 32768;          // 32768

    u16* xtb_t    = (u16*)f_xtb;
    u16* spcb     = (u16*)f_spcb;
    u16* Wcat_t   = (u16*)f_Wcat;
    u16* lin1b_t  = (u16*)f_lin1b;
    u16* lin2b_t  = (u16*)f_lin2b;
    u16* wcombb_t = (u16*)f_wcombb;
    u16* attn_ob  = xtb_t;   // xtb dead after gemm_fused

    prep<<<P1_BLOCKS, 256, 0, stream>>>(
        x, conv0_w, conv0_b, key_w, key_b, val_w, val_b, off_w, off_b,
        lin1_w, lin2_w, conv1_w, conv1_b, out_w, out_b, cam_emb,
        pos, xtb_t, mu_x, Wcat_t, bias_cat, lin1b_t, lin2b_t, wcombb_t,
        bcomb, camoff, posy, posx);
    gemm_fused<<<681, 256, 0, stream>>>(xtb_t, Wcat_t, bias_cat, pos, cam_emb,
                                        spcb, kvf, offs, mu_x, conv0_w,
                                        conv0_b, conv2_w, conv2_b, g);
    attn_kernel<<<LQ / 2, 256, 0, stream>>>(spcb, kvf, offs, posy, posx,
                                            camoff, g, attn_ob);
    epilogue<<<300, 256, 0, stream>>>(attn_ob, wcombb_t, bcomb, x,
                                      norm0_g, norm0_b, lin1b_t, lin1_b,
                                      lin2b_t, lin2_b, norm2_g, norm2_b,
                                      (float*)d_out);
}

// Round 12
// 202.396 us; speedup vs baseline: 1.0967x; 1.0967x over previous
//
#include <hip/hip_runtime.h>
#include <math.h>

typedef unsigned short u16;
typedef unsigned int u32;

#define NCAM 6
#define NHEADS 8
#define NPOINTS 4
#define DD 256
#define HH 20
#define WW 40
#define HWSZ 800
#define LQ 4800
#define HDIM 32

typedef __attribute__((ext_vector_type(8))) short bf16x8;
typedef __attribute__((ext_vector_type(4))) float f32x4;

__device__ __forceinline__ u16 f2b(float x) {
    union { float f; u32 u; } v;
    v.f = x;
    u32 r = (v.u + 0x7FFFu + ((v.u >> 16) & 1u)) >> 16;  // RNE
    return (u16)r;
}
__device__ __forceinline__ float lo2f(u32 u) {
    union { u32 u; float f; } v; v.u = u << 16; return v.f;
}
__device__ __forceinline__ float hi2f(u32 u) {
    union { u32 u; float f; } v; v.u = u & 0xFFFF0000u; return v.f;
}
__device__ __forceinline__ float red16(float s) {
    s += __shfl_xor(s, 1);
    s += __shfl_xor(s, 2);
    s += __shfl_xor(s, 4);
    s += __shfl_xor(s, 8);
    return s;
}
// async global->LDS, 16B per lane, dest = base + lane*16 (wave-uniform base)
__device__ __forceinline__ void gl_lds16(const void* g, void* l) {
    __builtin_amdgcn_global_load_lds(
        (const __attribute__((address_space(1))) void*)g,
        (__attribute__((address_space(3))) void*)l, 16, 0, 0);
}

// k-major layouts: elem(row,k) at ((k>>3)*NR + row)*8 + (k&7)

// ---------------------------------------------------------------------------
// prep: one-shot heterogeneous prep (identical to R9-passing version).
#define P1_BLOCKS 3362
__global__ __launch_bounds__(256) void prep(
    const float* __restrict__ x, const float* __restrict__ conv0_w,
    const float* __restrict__ conv0_b, const float* __restrict__ key_w,
    const float* __restrict__ key_b, const float* __restrict__ val_w,
    const float* __restrict__ val_b, const float* __restrict__ off_w,
    const float* __restrict__ off_b, const float* __restrict__ lin1_w,
    const float* __restrict__ lin2_w, const float* __restrict__ conv1_w,
    const float* __restrict__ conv1_b, const float* __restrict__ out_w,
    const float* __restrict__ out_b, const float* __restrict__ cam_emb,
    float* __restrict__ pos, u16* __restrict__ xtb_t, float* __restrict__ mu_x,
    u16* __restrict__ Wcat_t, float* __restrict__ bias_cat,
    u16* __restrict__ lin1b_t, u16* __restrict__ lin2b_t,
    u16* __restrict__ wcombb_t, float* __restrict__ bcomb,
    float* __restrict__ camoff, float* __restrict__ posy,
    float* __restrict__ posx) {
    __shared__ float sbuf[1088];
    __shared__ __align__(16) u16 As2[1024];
    __shared__ __align__(16) u16 Bs2[4096];
    int b = blockIdx.x, t = threadIdx.x;
    if (b < 800) {
        int hw = b, d = t;
        int h = hw / WW, w = hw % WW;
        int j = (d & 127) >> 1;
        float dim = powf(10000.0f, (float)j * (1.0f / 64.0f));
        float v;
        if (d < 128) v = (float)(h + 1) / (20.0f + 1e-6f) * (2.0f * (float)M_PI);
        else         v = (float)(w + 1) / (40.0f + 1e-6f) * (2.0f * (float)M_PI);
        float p = v / dim;
        pos[hw * DD + d] = (d & 1) ? cosf(p) : sinf(p);
    } else if (b < 1184) {
        int row = (b - 800) * 4 + (t >> 6);
        int lane = t & 63;
        const float* base = x + (size_t)row * HWSZ;
        float s = 0.f;
        for (int i = lane; i < HWSZ; i += 64) s += base[i];
#pragma unroll
        for (int m = 1; m <= 32; m <<= 1) s += __shfl_xor(s, m);
        if (lane == 0) mu_x[row] = s * (1.0f / (float)HWSZ);
    } else if (b < 1952) {
        int i = (b - 1184) * 256 + t;
        if (i < 65536) {
            int n = i >> 8, k = i & 255;
            Wcat_t[(((size_t)(k >> 3)) * 1152 + n) * 8 + (k & 7)] = f2b(conv0_w[i]);
            if (i < 256) bias_cat[i] = conv0_b[i];
        } else if (i < 131072) {
            int j = i - 65536;
            int n = j >> 8, k = j & 255;
            lin1b_t[(((size_t)(k >> 3)) * 256 + n) * 8 + (k & 7)] = f2b(lin1_w[j]);
        } else {
            int j = i - 131072;
            int n = j >> 8, k = j & 255;
            lin2b_t[(((size_t)(k >> 3)) * 256 + n) * 8 + (k & 7)] = f2b(lin2_w[j]);
        }
    } else if (b < 3152) {
        int idx = b - 1952;
        int cam = idx / 200, rem = idx % 200;
        int hw0 = (rem % 25) * 32, c0 = (rem / 25) * 32;
        float (*tile)[33] = (float(*)[33])sbuf;
        int lhw = t & 31, lc4 = t >> 5;
#pragma unroll
        for (int i = 0; i < 4; ++i) {
            int lc = lc4 * 4 + i;
            tile[lc][lhw] = x[((size_t)(cam * DD + c0 + lc)) * HWSZ + hw0 + lhw];
        }
        __syncthreads();
        int lc2 = t & 31, lhw4 = t >> 5;
        int c = c0 + lc2;
#pragma unroll
        for (int i = 0; i < 4; ++i) {
            int lhw2 = lhw4 * 4 + i;
            int row = cam * HWSZ + hw0 + lhw2;
            xtb_t[(((size_t)(c >> 3)) * 4800 + row) * 8 + (c & 7)] =
                f2b(tile[lc2][lhw2]);
        }
    } else if (b < 3212) {
        int idx = b - 3152;
        int yside = (idx < 20);
        int coord = yside ? idx : idx - 20;
        if (t < 128) {
            int d = t, j = d >> 1;
            float dim = powf(10000.0f, (float)j * (1.0f / 64.0f));
            float v = yside
                ? (float)(coord + 1) / (20.0f + 1e-6f) * (2.0f * (float)M_PI)
                : (float)(coord + 1) / (40.0f + 1e-6f) * (2.0f * (float)M_PI);
            float p = v / dim;
            sbuf[d] = (d & 1) ? cosf(p) : sinf(p);
        }
        __syncthreads();
        int koff = yside ? 0 : 128;
        float* outp = yside ? (posy + coord * 384) : (posx + coord * 384);
        int l = t & 15, og = t >> 4;
#pragma unroll
        for (int chunk = 0; chunk < 24; ++chunk) {
            int n = chunk * 16 + og;
            const float* wr = off_w + (size_t)n * 256 + koff + l * 8;
            float4 w0 = *(const float4*)wr;
            float4 w1 = *(const float4*)(wr + 4);
            const float* pv = sbuf + l * 8;
            float s = pv[0] * w0.x + pv[1] * w0.y + pv[2] * w0.z + pv[3] * w0.w +
                      pv[4] * w1.x + pv[5] * w1.y + pv[6] * w1.z + pv[7] * w1.w;
            s = red16(s);
            if (l == 0) outp[n] = s;
        }
    } else if (b < 3218) {
        int cam = b - 3212;
        sbuf[t] = cam_emb[cam * DD + t];
        __syncthreads();
        int l = t & 15, og = t >> 4;
#pragma unroll
        for (int chunk = 0; chunk < 24; ++chunk) {
            int n = chunk * 16 + og;
            const float* wr = off_w + (size_t)n * 256 + l * 16;
            float s = 0.f;
#pragma unroll
            for (int i = 0; i < 4; ++i) {
                float4 w4 = *(const float4*)(wr + i * 4);
                const float* ce = sbuf + l * 16 + i * 4;
                s += ce[0] * w4.x + ce[1] * w4.y + ce[2] * w4.z + ce[3] * w4.w;
            }
            s = red16(s);
            if (l == 0) camoff[cam * 384 + n] = s;
        }
    } else if (b < 3274) {
        sbuf[t] = conv0_b[t];
        __syncthreads();
        int l = t & 15, og = t >> 4;
        int rr = (b - 3218) * 16 + og;
        const float* srcp;
        float bsrc;
        if (rr < 512) {
            int head = rr >> 6, cpair = (rr >> 1) & 31, kv = rr & 1;
            srcp = (kv ? val_w : key_w) + (size_t)(head * 32 + cpair) * 256;
            bsrc = (kv ? val_b : key_b)[head * 32 + cpair];
        } else {
            srcp = off_w + (size_t)(rr - 512) * 256;
            bsrc = off_b[rr - 512];
        }
        float s = 0.f;
#pragma unroll
        for (int i = 0; i < 4; ++i) {
            float4 w4 = *(const float4*)(srcp + l * 16 + i * 4);
            const float* cb = sbuf + l * 16 + i * 4;
            s += cb[0] * w4.x + cb[1] * w4.y + cb[2] * w4.z + cb[3] * w4.w;
        }
        s = red16(s);
        if (l == 0) bias_cat[256 + rr] = bsrc + s;
    } else if (b < 3290) {
        sbuf[t] = out_b[t];
        __syncthreads();
        int l = t & 15, og = t >> 4;
        int n = (b - 3274) * 16 + og;
        float s = 0.f;
#pragma unroll
        for (int i = 0; i < 4; ++i) {
            float4 w4 = *(const float4*)(conv1_w + (size_t)n * 256 + l * 16 + i * 4);
            const float* ob = sbuf + l * 16 + i * 4;
            s += ob[0] * w4.x + ob[1] * w4.y + ob[2] * w4.z + ob[3] * w4.w;
        }
        s = red16(s);
        if (l == 0) bcomb[n] = conv1_b[n] + s;
    } else {
        int fb = b - 3290;
        int isw = (fb >= 56);
        int bb = isw ? fb - 56 : fb;
        int row0 = (bb >> 1) * 32, col0 = (bb & 1) * 128;
        int wv = t >> 6, lane = t & 63, quad = lane >> 4, l = lane & 15;
        f32x4 acc[2][2] = {};
        for (int k0 = 0; k0 < 256; k0 += 32) {
            __syncthreads();
            if (t < 128) {
                int m = t >> 2, j = t & 3;
                int rr = row0 + m;
                const float* ap;
                if (!isw) {
                    if (rr < 512) {
                        int head = rr >> 6, cpair = (rr >> 1) & 31, kv = rr & 1;
                        ap = (kv ? val_w : key_w) + (size_t)(head * 32 + cpair) * 256;
                    } else {
                        ap = off_w + (size_t)(rr - 512) * 256;
                    }
                } else {
                    ap = conv1_w + (size_t)rr * 256;
                }
                float4 f0 = *(const float4*)&ap[k0 + j * 8];
                float4 f1 = *(const float4*)&ap[k0 + j * 8 + 4];
                uint4 up;
                up.x = (u32)f2b(f0.x) | ((u32)f2b(f0.y) << 16);
                up.y = (u32)f2b(f0.z) | ((u32)f2b(f0.w) << 16);
                up.z = (u32)f2b(f1.x) | ((u32)f2b(f1.y) << 16);
                up.w = (u32)f2b(f1.z) | ((u32)f2b(f1.w) << 16);
                *(uint4*)&As2[(j * 32 + m) * 8] = up;
            }
            {
                int krel = t >> 3;
                int k = k0 + krel;
                int j = t >> 6, kin = k & 7;
                int c0l = (t & 7) * 16;
                const float* wsrc = (isw ? out_w : conv0_w) + (size_t)k * 256 + col0 + c0l;
#pragma unroll
                for (int i = 0; i < 16; i += 4) {
                    float4 f = *(const float4*)&wsrc[i];
                    Bs2[(j * 128 + c0l + i) * 8 + kin]     = f2b(f.x);
                    Bs2[(j * 128 + c0l + i + 1) * 8 + kin] = f2b(f.y);
                    Bs2[(j * 128 + c0l + i + 2) * 8 + kin] = f2b(f.z);
                    Bs2[(j * 128 + c0l + i + 3) * 8 + kin] = f2b(f.w);
                }
            }
            __syncthreads();
            bf16x8 a0 = *(const bf16x8*)&As2[(quad * 32 + l) * 8];
            bf16x8 a1 = *(const bf16x8*)&As2[(quad * 32 + 16 + l) * 8];
            bf16x8 b0v = *(const bf16x8*)&Bs2[(quad * 128 + wv * 32 + l) * 8];
            bf16x8 b1v = *(const bf16x8*)&Bs2[(quad * 128 + wv * 32 + 16 + l) * 8];
            acc[0][0] = __builtin_amdgcn_mfma_f32_16x16x32_bf16(a0, b0v, acc[0][0], 0, 0, 0);
            acc[0][1] = __builtin_amdgcn_mfma_f32_16x16x32_bf16(a0, b1v, acc[0][1], 0, 0, 0);
            acc[1][0] = __builtin_amdgcn_mfma_f32_16x16x32_bf16(a1, b0v, acc[1][0], 0, 0, 0);
            acc[1][1] = __builtin_amdgcn_mfma_f32_16x16x32_bf16(a1, b1v, acc[1][1], 0, 0, 0);
        }
#pragma unroll
        for (int mt = 0; mt < 2; ++mt) {
#pragma unroll
            for (int nt = 0; nt < 2; ++nt) {
                int c = col0 + wv * 32 + nt * 16 + l;
#pragma unroll
                for (int r = 0; r < 4; ++r) {
                    int rr = row0 + mt * 16 + quad * 4 + r;
                    u16 ov = f2b(acc[mt][nt][r]);
                    if (!isw)
                        Wcat_t[(((size_t)(c >> 3)) * 1152 + 256 + rr) * 8 + (c & 7)] = ov;
                    else
                        wcombb_t[(((size_t)(c >> 3)) * 256 + rr) * 8 + (c & 7)] = ov;
                }
            }
        }
    }
}

// ---------------------------------------------------------------------------
// gemm_fused (identical to R9-passing version: kv bf16 interleaved)
__global__ __launch_bounds__(256) void gemm_fused(
    const u16* __restrict__ Abt, const u16* __restrict__ Wcat_t,
    const float* __restrict__ bias_cat, const float* __restrict__ pos,
    const float* __restrict__ cam_emb, u16* __restrict__ spcb,
    u16* __restrict__ kvcat16, float* __restrict__ offs,
    const float* __restrict__ mu_x, const float* __restrict__ conv0_w,
    const float* __restrict__ conv0_b, const float* __restrict__ conv2_w,
    const float* __restrict__ conv2_b, float* __restrict__ g) {
    int b = blockIdx.x, t = threadIdx.x;
    if (b < 675) {
        __shared__ __align__(16) u16 As[2048];
        __shared__ __align__(16) u16 Bs[4096];
        int col0 = (b % 9) * 128, row0 = (b / 9) * 64;
        int wv = t >> 6, lane = t & 63;
        int quad = lane >> 4, l = lane & 15;
        f32x4 acc[4][2] = {};
        for (int kg = 0; kg < 32; kg += 4) {
            __syncthreads();
            gl_lds16(Abt + (((size_t)(kg + wv)) * 4800 + row0 + lane) * 8,
                     &As[wv * 64 * 8]);
            int jb = wv >> 1, hb = wv & 1;
            gl_lds16(Wcat_t + (((size_t)(kg + jb)) * 1152 + col0 + hb * 64 + lane) * 8,
                     &Bs[(jb * 128 + hb * 64) * 8]);
            gl_lds16(Wcat_t + (((size_t)(kg + 2 + jb)) * 1152 + col0 + hb * 64 + lane) * 8,
                     &Bs[((2 + jb) * 128 + hb * 64) * 8]);
            __syncthreads();
            bf16x8 b0 = *(const bf16x8*)&Bs[(quad * 128 + wv * 32 + l) * 8];
            bf16x8 b1 = *(const bf16x8*)&Bs[(quad * 128 + wv * 32 + 16 + l) * 8];
#pragma unroll
            for (int mt = 0; mt < 4; ++mt) {
                bf16x8 a = *(const bf16x8*)&As[(quad * 64 + mt * 16 + l) * 8];
                acc[mt][0] = __builtin_amdgcn_mfma_f32_16x16x32_bf16(a, b0, acc[mt][0], 0, 0, 0);
                acc[mt][1] = __builtin_amdgcn_mfma_f32_16x16x32_bf16(a, b1, acc[mt][1], 0, 0, 0);
            }
        }
#pragma unroll
        for (int mt = 0; mt < 4; ++mt) {
#pragma unroll
            for (int nt = 0; nt < 2; ++nt) {
                int col = col0 + wv * 32 + nt * 16 + l;
                float bb = bias_cat[col];
#pragma unroll
                for (int r = 0; r < 4; ++r) {
                    int row = row0 + mt * 16 + quad * 4 + r;
                    float v = acc[mt][nt][r] + bb;
                    if (col0 < 256) {
                        int cam = row / HWSZ, hw = row % HWSZ;
                        spcb[(size_t)row * 256 + col] =
                            f2b(v + pos[(size_t)hw * 256 + col] + cam_emb[cam * 256 + col]);
                    } else if (col0 < 768) {
                        kvcat16[(size_t)row * 512 + (col - 256)] = f2b(v);
                    } else {
                        offs[(size_t)row * 384 + (col - 768)] = v;
                    }
                }
            }
        }
    } else {
        int cam = b - 675;
        __shared__ float mu[DD];
        __shared__ float smu[DD];
        float pm;
        {
            int d = t;
            int j = (d & 127) >> 1;
            float inv = 1.0f / powf(10000.0f, (float)j * (1.0f / 64.0f));
            float s = 0.f;
            if (d < 128) {
                for (int h = 0; h < HH; ++h) {
                    float p = (float)(h + 1) / (20.0f + 1e-6f) * (2.0f * (float)M_PI) * inv;
                    s += (d & 1) ? cosf(p) : sinf(p);
                }
                pm = s * (1.0f / (float)HH);
            } else {
                for (int w = 0; w < WW; ++w) {
                    float p = (float)(w + 1) / (40.0f + 1e-6f) * (2.0f * (float)M_PI) * inv;
                    s += (d & 1) ? cosf(p) : sinf(p);
                }
                pm = s * (1.0f / (float)WW);
            }
        }
        mu[t] = mu_x[cam * DD + t];
        __syncthreads();
        float a = conv0_b[t] + pm + cam_emb[cam * DD + t];
        const float* wr = conv0_w + (size_t)t * DD;
        for (int k = 0; k < DD; ++k) a += mu[k] * wr[k];
        smu[t] = a;
        __syncthreads();
        float ga = conv2_b[t];
        const float* w2r = conv2_w + (size_t)t * DD;
        for (int d = 0; d < DD; ++d) ga += smu[d] * w2r[d];
        g[cam * DD + t] = ga;
    }
}

// ---------------------------------------------------------------------------
// Deformable attention: R9-proven structure (2 q/block, 16 lanes/head, bf16 kv)
// + packed uint2 (weight,index) metadata with conflict-free head pitch 101.
// Head h base bank = (101*2*h) mod 32 = {0,10,20,30,8,18,28,6} -> all distinct.
__global__ __launch_bounds__(256, 6) void attn_kernel(
    const u16* __restrict__ spcb, const u16* __restrict__ kvcat16,
    const float* __restrict__ offs, const float* __restrict__ posy,
    const float* __restrict__ posx, const float* __restrict__ camoff,
    const float* __restrict__ g, u16* __restrict__ attn_out) {
    int qq = blockIdx.x;
    int q0 = qq * 2;
    int tid = threadIdx.x;
    int cam = q0 / HWSZ;
    int hw0 = q0 % HWSZ;
    __shared__ float soff[2][384];
    __shared__ uint2 widx[2][808];   // [qi][head*101 + r*4 + j]
    for (int i = tid; i < 768; i += 256) {
        int qi = i / 384, n = i - qi * 384;
        int hw = hw0 + qi;
        int h = hw / WW, w = hw - h * WW;
        soff[qi][n] = offs[(size_t)(q0 + qi) * 384 + n] + posy[h * 384 + n] +
                      posx[w * 384 + n] + camoff[cam * 384 + n];
    }
    __syncthreads();
    for (int e2 = tid; e2 < 384; e2 += 256) {
        int qi = e2 / 192, e = e2 - qi * 192;
        int head = e / 24, r = e - head * 24;
        int scam = r >> 2;
        int hw = hw0 + qi;
        int h = hw / WW, w = hw - h * WW;
        float X = (float)w + soff[qi][e * 2];
        float Y = (float)h + soff[qi][e * 2 + 1];
        float x0f = floorf(X), y0f = floorf(Y);
        float fx = X - x0f, fy = Y - y0f;
        int x0 = (int)x0f, y0 = (int)y0f, x1 = x0 + 1, y1 = y0 + 1;
        float vx0 = (x0 >= 0 && x0 < WW) ? 1.f : 0.f;
        float vx1 = (x1 >= 0 && x1 < WW) ? 1.f : 0.f;
        float vy0 = (y0 >= 0 && y0 < HH) ? 1.f : 0.f;
        float vy1 = (y1 >= 0 && y1 < HH) ? 1.f : 0.f;
        int cx0 = min(max(x0, 0), WW - 1), cx1 = min(max(x1, 0), WW - 1);
        int cy0 = min(max(y0, 0), HH - 1), cy1 = min(max(y1, 0), HH - 1);
        int pb = scam * HWSZ, hb = head * 64;
        int base = head * 101 + r * 4;
        widx[qi][base + 0] = make_uint2(
            __float_as_uint((1.f - fx) * (1.f - fy) * vx0 * vy0),
            (u32)(((pb + cy0 * WW + cx0) << 9) + hb));
        widx[qi][base + 1] = make_uint2(
            __float_as_uint(fx * (1.f - fy) * vx1 * vy0),
            (u32)(((pb + cy0 * WW + cx1) << 9) + hb));
        widx[qi][base + 2] = make_uint2(
            __float_as_uint((1.f - fx) * fy * vx0 * vy1),
            (u32)(((pb + cy1 * WW + cx0) << 9) + hb));
        widx[qi][base + 3] = make_uint2(
            __float_as_uint(fx * fy * vx1 * vy1),
            (u32)(((pb + cy1 * WW + cx1) << 9) + hb));
    }
    __syncthreads();
    int qi = tid >> 7, head = (tid >> 4) & 7, l = tid & 15;
    int q = q0 + qi;
    int c0 = l * 2;
    u32 qu = *(const u32*)&spcb[(size_t)q * 256 + head * 32 + c0];
    const float scale = 0.17677669529663687f;  // 1/sqrt(32)
    float q0s = lo2f(qu) * scale, q1s = hi2f(qu) * scale;
    float m = -1e30f, den = 0.f, o0 = 0.f, o1 = 0.f;
    int l4 = 4 * l;
    int mbase = head * 101;
    for (int scp = 0; scp < 3; ++scp) {
        int eb0 = mbase + scp * 32;
        float av0[8], av1[8], lg[8];
#pragma unroll
        for (int p = 0; p < 8; ++p) {
            int eb = eb0 + p * 4;
            float ak0 = 0.f, ak1 = 0.f, a0 = 0.f, a1 = 0.f;
#pragma unroll
            for (int j = 0; j < 4; ++j) {
                uint2 wi = widx[qi][eb + j];
                float wj = __uint_as_float(wi.x);
                int idx = (int)wi.y + l4;
                uint2 d = *(const uint2*)&kvcat16[idx];  // k0,v0,k1,v1
                ak0 += wj * lo2f(d.x);
                a0  += wj * hi2f(d.x);
                ak1 += wj * lo2f(d.y);
                a1  += wj * hi2f(d.y);
            }
            av0[p] = a0; av1[p] = a1;
            float pl = q0s * ak0 + q1s * ak1;
            lg[p] = red16(pl);
        }
        float2 gva = *(const float2*)&g[(scp * 2) * 256 + head * 32 + c0];
        float2 gvb = *(const float2*)&g[(scp * 2 + 1) * 256 + head * 32 + c0];
        float pga = red16(q0s * gva.x + q1s * gva.y);
        float pgb = red16(q0s * gvb.x + q1s * gvb.y);
        float mc = fmaxf(pga, pgb);
#pragma unroll
        for (int p = 0; p < 8; ++p) mc = fmaxf(mc, lg[p]);
        float mn = fmaxf(m, mc);
        float aa = __expf(m - mn);
        float ee[8];
        float dsum = 0.f, s0 = 0.f, s1 = 0.f;
#pragma unroll
        for (int p = 0; p < 8; ++p) {
            ee[p] = __expf(lg[p] - mn);
            dsum += ee[p];
            s0 += ee[p] * av0[p];
            s1 += ee[p] * av1[p];
        }
        float ea = __expf(pga - mn), eb = __expf(pgb - mn);
        dsum += ea + eb;
        s0 += ea * gva.x + eb * gvb.x;
        s1 += ea * gva.y + eb * gvb.y;
        den = den * aa + dsum;
        o0 = o0 * aa + s0;
        o1 = o1 * aa + s1;
        m = mn;
    }
    float inv = 1.f / den;
    u32 pack = (u32)f2b(o0 * inv) | ((u32)f2b(o1 * inv) << 16);
    *(u32*)&attn_out[(size_t)q * 256 + head * 32 + c0] = pack;
}

// ---------------------------------------------------------------------------
// Mega-epilogue (identical to R9-passing version)
__global__ __launch_bounds__(256) void epilogue(
    const u16* __restrict__ Ab, const u16* __restrict__ Wc_t,
    const float* __restrict__ bcomb, const float* __restrict__ x_nchw,
    const float* __restrict__ n0g, const float* __restrict__ n0b,
    const u16* __restrict__ W1_t, const float* __restrict__ b1v,
    const u16* __restrict__ W2_t, const float* __restrict__ b2v,
    const float* __restrict__ n2g, const float* __restrict__ n2b,
    float* __restrict__ out_nchw) {
    __shared__ __align__(16) u16 As[552];
    __shared__ __align__(16) u16 Bs[8192];
    __shared__ __align__(16) u16 A2[4360];
    __shared__ float red[4][4][4][2];
    int t = threadIdx.x;
    int row0 = blockIdx.x * 16;
    int wv = t >> 6, lane = t & 63, quad = lane >> 4, l = lane & 15;
    int cam = row0 / HWSZ;
    int hw0q = row0 % HWSZ + quad * 4;

    f32x4 acc[4] = {};
    for (int kg = 0; kg < 32; kg += 4) {
        __syncthreads();
        if (t < 64) {
            int mm = t >> 2, j = t & 3;
            *(uint4*)&As[(j * 17 + mm) * 8] =
                *(const uint4*)&Ab[(size_t)(row0 + mm) * 256 + kg * 8 + j * 8];
        }
#pragma unroll
        for (int s = 0; s < 4; ++s)
            gl_lds16(Wc_t + (((size_t)(kg + wv)) * 256 + s * 64 + lane) * 8,
                     &Bs[(wv * 256 + s * 64) * 8]);
        __syncthreads();
        bf16x8 a = *(const bf16x8*)&As[(quad * 17 + l) * 8];
#pragma unroll
        for (int nt = 0; nt < 4; ++nt) {
            bf16x8 b = *(const bf16x8*)&Bs[(quad * 256 + wv * 64 + nt * 16 + l) * 8];
            acc[nt] = __builtin_amdgcn_mfma_f32_16x16x32_bf16(a, b, acc[nt], 0, 0, 0);
        }
    }
    float v[4][4];
    int cols[4];
#pragma unroll
    for (int nt = 0; nt < 4; ++nt) {
        int col = wv * 64 + nt * 16 + l;
        cols[nt] = col;
        float bb = bcomb[col];
        float4 rx = *(const float4*)&x_nchw[((size_t)(cam * 256 + col)) * HWSZ + hw0q];
        v[nt][0] = acc[nt][0] + bb + rx.x;
        v[nt][1] = acc[nt][1] + bb + rx.y;
        v[nt][2] = acc[nt][2] + bb + rx.z;
        v[nt][3] = acc[nt][3] + bb + rx.w;
    }
#pragma unroll
    for (int r = 0; r < 4; ++r) {
        float s = v[0][r] + v[1][r] + v[2][r] + v[3][r];
        float sq = v[0][r] * v[0][r] + v[1][r] * v[1][r] +
                   v[2][r] * v[2][r] + v[3][r] * v[3][r];
#pragma unroll
        for (int msk = 1; msk <= 8; msk <<= 1) {
            s += __shfl_xor(s, msk);
            sq += __shfl_xor(sq, msk);
        }
        if (l == 0) { red[wv][quad][r][0] = s; red[wv][quad][r][1] = sq; }
    }
    __syncthreads();
    float o0[4][4];
#pragma unroll
    for (int r = 0; r < 4; ++r) {
        float S = red[0][quad][r][0] + red[1][quad][r][0] +
                  red[2][quad][r][0] + red[3][quad][r][0];
        float Q = red[0][quad][r][1] + red[1][quad][r][1] +
                  red[2][quad][r][1] + red[3][quad][r][1];
        float mean = S * (1.0f / 256.0f);
        float var = Q * (1.0f / 256.0f) - mean * mean;
        float rstd = rsqrtf(var + 1e-5f);
        int row = quad * 4 + r;
#pragma unroll
        for (int nt = 0; nt < 4; ++nt) {
            int col = cols[nt];
            float ov = (v[nt][r] - mean) * rstd * n0g[col] + n0b[col];
            o0[nt][r] = ov;
            A2[((col >> 3) * 17 + row) * 8 + (col & 7)] = f2b(ov);
        }
    }
    f32x4 acc2[4] = {};
    for (int kg = 0; kg < 32; kg += 4) {
        __syncthreads();
#pragma unroll
        for (int s = 0; s < 4; ++s)
            gl_lds16(W1_t + (((size_t)(kg + wv)) * 256 + s * 64 + lane) * 8,
                     &Bs[(wv * 256 + s * 64) * 8]);
        __syncthreads();
        bf16x8 a = *(const bf16x8*)&A2[((kg + quad) * 17 + l) * 8];
#pragma unroll
        for (int nt = 0; nt < 4; ++nt) {
            bf16x8 b = *(const bf16x8*)&Bs[(quad * 256 + wv * 64 + nt * 16 + l) * 8];
            acc2[nt] = __builtin_amdgcn_mfma_f32_16x16x32_bf16(a, b, acc2[nt], 0, 0, 0);
        }
    }
    __syncthreads();
#pragma unroll
    for (int nt = 0; nt < 4; ++nt) {
        int col = cols[nt];
        float bb = b1v[col];
#pragma unroll
        for (int r = 0; r < 4; ++r) {
            int row = quad * 4 + r;
            A2[((col >> 3) * 17 + row) * 8 + (col & 7)] = f2b(fmaxf(acc2[nt][r] + bb, 0.f));
        }
    }
    f32x4 acc3[4] = {};
    for (int kg = 0; kg < 32; kg += 4) {
        __syncthreads();
#pragma unroll
        for (int s = 0; s < 4; ++s)
            gl_lds16(W2_t + (((size_t)(kg + wv)) * 256 + s * 64 + lane) * 8,
                     &Bs[(wv * 256 + s * 64) * 8]);
        __syncthreads();
        bf16x8 a = *(const bf16x8*)&A2[((kg + quad) * 17 + l) * 8];
#pragma unroll
        for (int nt = 0; nt < 4; ++nt) {
            bf16x8 b = *(const bf16x8*)&Bs[(quad * 256 + wv * 64 + nt * 16 + l) * 8];
            acc3[nt] = __builtin_amdgcn_mfma_f32_16x16x32_bf16(a, b, acc3[nt], 0, 0, 0);
        }
    }
    float v2[4][4];
#pragma unroll
    for (int nt = 0; nt < 4; ++nt) {
        float bb = b2v[cols[nt]];
#pragma unroll
        for (int r = 0; r < 4; ++r) v2[nt][r] = acc3[nt][r] + bb + o0[nt][r];
    }
    __syncthreads();
#pragma unroll
    for (int r = 0; r < 4; ++r) {
        float s = v2[0][r] + v2[1][r] + v2[2][r] + v2[3][r];
        float sq = v2[0][r] * v2[0][r] + v2[1][r] * v2[1][r] +
                   v2[2][r] * v2[2][r] + v2[3][r] * v2[3][r];
#pragma unroll
        for (int msk = 1; msk <= 8; msk <<= 1) {
            s += __shfl_xor(s, msk);
            sq += __shfl_xor(sq, msk);
        }
        if (l == 0) { red[wv][quad][r][0] = s; red[wv][quad][r][1] = sq; }
    }
    __syncthreads();
    float mean2[4], rstd2[4];
#pragma unroll
    for (int r = 0; r < 4; ++r) {
        float S = red[0][quad][r][0] + red[1][quad][r][0] +
                  red[2][quad][r][0] + red[3][quad][r][0];
        float Q = red[0][quad][r][1] + red[1][quad][r][1] +
                  red[2][quad][r][1] + red[3][quad][r][1];
        mean2[r] = S * (1.0f / 256.0f);
        float var = Q * (1.0f / 256.0f) - mean2[r] * mean2[r];
        rstd2[r] = rsqrtf(var + 1e-5f);
    }
#pragma unroll
    for (int nt = 0; nt < 4; ++nt) {
        int col = cols[nt];
        float gg = n2g[col], bb = n2b[col];
        float4 ov4;
        ov4.x = (v2[nt][0] - mean2[0]) * rstd2[0] * gg + bb;
        ov4.y = (v2[nt][1] - mean2[1]) * rstd2[1] * gg + bb;
        ov4.z = (v2[nt][2] - mean2[2]) * rstd2[2] * gg + bb;
        ov4.w = (v2[nt][3] - mean2[3]) * rstd2[3] * gg + bb;
        *(float4*)&out_nchw[((size_t)(cam * 256 + col)) * HWSZ + hw0q] = ov4;
    }
}

// ---------------------------------------------------------------------------
extern "C" void kernel_launch(void* const* d_in, const int* in_sizes, int n_in,
                              void* d_out, int out_size, void* d_ws, size_t ws_size,
                              hipStream_t stream) {
    const float* x       = (const float*)d_in[0];
    const float* conv0_w = (const float*)d_in[1];
    const float* conv0_b = (const float*)d_in[2];
    const float* conv2_w = (const float*)d_in[3];
    const float* conv2_b = (const float*)d_in[4];
    const float* cam_emb = (const float*)d_in[5];
    const float* off_w   = (const float*)d_in[6];
    const float* off_b   = (const float*)d_in[7];
    const float* val_w   = (const float*)d_in[8];
    const float* val_b   = (const float*)d_in[9];
    const float* key_w   = (const float*)d_in[10];
    const float* key_b   = (const float*)d_in[11];
    const float* out_w   = (const float*)d_in[12];
    const float* out_b   = (const float*)d_in[13];
    const float* conv1_w = (const float*)d_in[14];
    const float* conv1_b = (const float*)d_in[15];
    const float* norm0_g = (const float*)d_in[16];
    const float* norm0_b = (const float*)d_in[17];
    const float* lin1_w  = (const float*)d_in[18];
    const float* lin1_b  = (const float*)d_in[19];
    const float* lin2_w  = (const float*)d_in[20];
    const float* lin2_b  = (const float*)d_in[21];
    const float* norm2_g = (const float*)d_in[22];
    const float* norm2_b = (const float*)d_in[23];

    float* ws = (float*)d_ws;
    float* pos      = ws;                       // 204800
    float* mu_x     = pos + 204800;             // 1536
    float* g        = mu_x + 1536;              // 1536
    float* camoff   = g + 1536;                 // 2304
    float* posy     = camoff + 2304;            // 7680
    float* posx     = posy + 7680;              // 15360
    float* bias_cat = posx + 15360;             // 1152
    float* bcomb    = bias_cat + 1152;          // 256
    float* offs     = bcomb + 256;              // 1843200
    float* f_xtb    = offs + 1843200;           // 614400 (alias: attn_ob)
    float* f_spcb   = f_xtb + 614400;           // 614400
    float* f_kvcat  = f_spcb + 614400;          // 1228800
    float* f_Wcat   = f_kvcat + 1228800;        // 147456
    float* f_lin1b  = f_Wcat + 147456;          // 32768
    float* f_lin2b  = f_lin1b + 32768;          // 32768
    float* f_wcombb = f_lin2b + 32768;          // 32768

    u16* xtb_t    = (u16*)f_xtb;
    u16* spcb     = (u16*)f_spcb;
    u16* kvcat16  = (u16*)f_kvcat;
    u16* Wcat_t   = (u16*)f_Wcat;
    u16* lin1b_t  = (u16*)f_lin1b;
    u16* lin2b_t  = (u16*)f_lin2b;
    u16* wcombb_t = (u16*)f_wcombb;
    u16* attn_ob  = xtb_t;   // xtb dead after gemm_fused

    prep<<<P1_BLOCKS, 256, 0, stream>>>(
        x, conv0_w, conv0_b, key_w, key_b, val_w, val_b, off_w, off_b,
        lin1_w, lin2_w, conv1_w, conv1_b, out_w, out_b, cam_emb,
        pos, xtb_t, mu_x, Wcat_t, bias_cat, lin1b_t, lin2b_t, wcombb_t,
        bcomb, camoff, posy, posx);
    gemm_fused<<<681, 256, 0, stream>>>(xtb_t, Wcat_t, bias_cat, pos, cam_emb,
                                        spcb, kvcat16, offs, mu_x, conv0_w,
                                        conv0_b, conv2_w, conv2_b, g);
    attn_kernel<<<LQ / 2, 256, 0, stream>>>(spcb, kvcat16, offs, posy, posx,
                                            camoff, g, attn_ob);
    epilogue<<<300, 256, 0, stream>>>(attn_ob, wcombb_t, bcomb, x,
                                      norm0_g, norm0_b, lin1b_t, lin1_b,
                                      lin2b_t, lin2_b, norm2_g, norm2_b,
                                      (float*)d_out);
}